// Round 4
// baseline (1083.195 us; speedup 1.0000x reference)
//
#include <hip/hip_runtime.h>
#include <hip/hip_bf16.h>
#include <hip/hip_cooperative_groups.h>

namespace cg = cooperative_groups;

#define IN_CH 512
#define OUT_CH 64

typedef __attribute__((ext_vector_type(8))) short short8;
typedef __attribute__((ext_vector_type(4))) float f32x4;

static __device__ __forceinline__ unsigned short bf16bits(float f) {
    __hip_bfloat16 h = __float2bfloat16(f);
    return *reinterpret_cast<unsigned short*>(&h);
}
static __device__ __forceinline__ float bflo(unsigned int u) { return __uint_as_float(u << 16); }
static __device__ __forceinline__ float bfhi(unsigned int u) { return __uint_as_float(u & 0xffff0000u); }

// ============ coop1: setup + degree + scan + CSR fill, one resident kernel ============
__global__ void __launch_bounds__(256, 4) coop1_kernel(
    const float* __restrict__ W, const int* __restrict__ ei,
    unsigned int* cnt, unsigned int* cursor, unsigned int* rowptr,
    unsigned int* wavesum, unsigned int* waveoff, float* dinv,
    unsigned int* srcIdx, unsigned short* Wt, unsigned short* hs,
    int N, int E)
{
    cg::grid_group grid = cg::this_grid();
    const int tid = blockIdx.x * 256 + threadIdx.x;
    const int nthreads = gridDim.x * 256;
    const int lane = threadIdx.x & 63;
    const int gwid = tid >> 6;
    const int nwaves = nthreads >> 6;

    // --- Phase A: zero cnt; W -> Wt (bf16, transposed); zero hs sentinel row N ---
    for (int i = tid; i < N; i += nthreads) cnt[i] = 0;
    for (int i = tid; i < IN_CH * OUT_CH; i += nthreads) {
        int k = i >> 6, n = i & 63;
        Wt[n * IN_CH + k] = bf16bits(W[i]);
    }
    if (tid < OUT_CH / 2) ((unsigned int*)(hs + (size_t)N * OUT_CH))[tid] = 0u;
    grid.sync();

    // --- Phase B: in-degree histogram ---
    {
        const int* col = ei + E;
        int E4 = E >> 2;
        for (int i = tid; i < E4; i += nthreads) {
            int4 c = ((const int4*)col)[i];
            atomicAdd(&cnt[c.x], 1u); atomicAdd(&cnt[c.y], 1u);
            atomicAdd(&cnt[c.z], 1u); atomicAdd(&cnt[c.w], 1u);
        }
        if (tid == 0) for (int e = E4 << 2; e < E; ++e) atomicAdd(&cnt[col[e]], 1u);
    }
    grid.sync();

    // --- Phase C1: dinv + wave-level inclusive scan of padded counts (1 node/thread) ---
    unsigned int v = 0;
    if (tid < N) {
        v = cnt[tid];
        dinv[tid] = rsqrtf((float)(v + 1u));
    }
    unsigned int pv = (v + 7u) & ~7u;
    unsigned int si = pv;
#pragma unroll
    for (int off = 1; off < 64; off <<= 1) {
        unsigned int o = __shfl_up(si, off, 64);
        if (lane >= off) si += o;
    }
    if (lane == 63) wavesum[gwid] = si;
    grid.sync();

    // --- Phase C2: block 0 exclusive-scans the wave sums ---
    if (blockIdx.x == 0) {
        __shared__ unsigned int ws4[4];
        int per = (nwaves + 255) >> 8;
        int base = threadIdx.x * per;
        unsigned int run = 0;
        for (int j = 0; j < per; ++j) {
            int idx = base + j;
            if (idx < nwaves) run += wavesum[idx];
        }
        unsigned int bs = run, bsi = bs;
#pragma unroll
        for (int off = 1; off < 64; off <<= 1) {
            unsigned int o = __shfl_up(bsi, off, 64);
            if ((threadIdx.x & 63) >= off) bsi += o;
        }
        if ((threadIdx.x & 63) == 63) ws4[threadIdx.x >> 6] = bsi;
        __syncthreads();
        unsigned int woff = 0;
        for (int k = 0; k < (int)(threadIdx.x >> 6); ++k) woff += ws4[k];
        unsigned int acc = woff + bsi - bs;
        for (int j = 0; j < per; ++j) {
            int idx = base + j;
            if (idx < nwaves) {
                unsigned int w = wavesum[idx];
                waveoff[idx] = acc;
                acc += w;
            }
        }
    }
    grid.sync();

    // --- Phase C3: rowptr; seed cursor = rowptr; sentinel-fill padding slots ---
    if (tid < N) {
        unsigned int start = waveoff[gwid] + (si - pv);
        rowptr[tid] = start;
        cursor[tid] = start;
        for (unsigned int j = v; j < pv; ++j) srcIdx[start + j] = (unsigned int)N;
    }
    grid.sync();

    // --- Phase D: CSR fill (cursor pre-seeded with start => single atomic per edge) ---
    {
        int E4 = E >> 2;
        for (int i = tid; i < E4; i += nthreads) {
            int4 r = ((const int4*)ei)[i];
            int4 c = ((const int4*)(ei + E))[i];
            unsigned int pos;
            pos = atomicAdd(&cursor[c.x], 1u); srcIdx[pos] = (unsigned int)r.x;
            pos = atomicAdd(&cursor[c.y], 1u); srcIdx[pos] = (unsigned int)r.y;
            pos = atomicAdd(&cursor[c.z], 1u); srcIdx[pos] = (unsigned int)r.z;
            pos = atomicAdd(&cursor[c.w], 1u); srcIdx[pos] = (unsigned int)r.w;
        }
        if (tid == 0) for (int e = E4 << 2; e < E; ++e) {
            int r = ei[e], c = ei[E + e];
            unsigned int pos = atomicAdd(&cursor[c], 1u);
            srcIdx[pos] = (unsigned int)r;
        }
    }
}

// ============ MFMA bf16 GEMM: hs = bf16((x @ W) * dinv[row]) ============
__global__ void __launch_bounds__(256) gemm_mfma(const float* __restrict__ x,
                                                 const unsigned short* __restrict__ Wt,
                                                 const float* __restrict__ dinv,
                                                 unsigned short* __restrict__ hs, int N) {
    int wid = (int)((blockIdx.x * (unsigned long long)blockDim.x + threadIdx.x) >> 6);
    int lane = threadIdx.x & 63;
    int row0 = wid * 16;
    if (row0 >= N) return;
    int m = lane & 15, q = lane >> 4;
    const float* xr = x + (size_t)(row0 + m) * IN_CH + q * 8;
    f32x4 acc[4];
#pragma unroll
    for (int t = 0; t < 4; ++t) acc[t] = (f32x4){0.f, 0.f, 0.f, 0.f};

    for (int kb = 0; kb < IN_CH; kb += 32) {
        f32x4 a0 = *(const f32x4*)(xr + kb);
        f32x4 a1 = *(const f32x4*)(xr + kb + 4);
        short8 af;
        af[0] = (short)bf16bits(a0[0]); af[1] = (short)bf16bits(a0[1]);
        af[2] = (short)bf16bits(a0[2]); af[3] = (short)bf16bits(a0[3]);
        af[4] = (short)bf16bits(a1[0]); af[5] = (short)bf16bits(a1[1]);
        af[6] = (short)bf16bits(a1[2]); af[7] = (short)bf16bits(a1[3]);
#pragma unroll
        for (int t = 0; t < 4; ++t) {
            short8 bf = *(const short8*)(Wt + (size_t)(t * 16 + m) * IN_CH + kb + q * 8);
            acc[t] = __builtin_amdgcn_mfma_f32_16x16x32_bf16(af, bf, acc[t], 0, 0, 0);
        }
    }
    // C/D layout: col = lane&15, row (within 16) = q*4 + reg
#pragma unroll
    for (int r = 0; r < 4; ++r) {
        float dr = dinv[row0 + q * 4 + r];
#pragma unroll
        for (int t = 0; t < 4; ++t)
            hs[(size_t)(row0 + q * 4 + r) * OUT_CH + t * 16 + m] = bf16bits(acc[t][r] * dr);
    }
}

// ============ gather + self + bias + log_softmax (full occupancy) ============
__global__ void __launch_bounds__(256) gather_kernel(const unsigned int* __restrict__ srcIdx,
                                                     const unsigned int* __restrict__ rowptr,
                                                     const unsigned int* __restrict__ cnt,
                                                     const float* __restrict__ dinv,
                                                     const unsigned short* __restrict__ hs,
                                                     const float* __restrict__ bias,
                                                     float* __restrict__ out, int N) {
    int node = (int)((blockIdx.x * (unsigned long long)blockDim.x + threadIdx.x) >> 6);
    int lane = threadIdx.x & 63;
    if (node >= N) return;
    int sub = lane >> 5, ch2 = lane & 31;
    unsigned int start = rowptr[node];
    unsigned int len = cnt[node];
    unsigned int iters = (len + 7u) >> 3;
    const uint4* sp = (const uint4*)(srcIdx + start) + sub;
    float acc0 = 0.f, acc1 = 0.f;
    unsigned int Nclamp = (unsigned int)N;
    for (unsigned int it = 0; it < iters; ++it) {
        uint4 iv = sp[it * 2];
        iv.x = min(iv.x, Nclamp); iv.y = min(iv.y, Nclamp);
        iv.z = min(iv.z, Nclamp); iv.w = min(iv.w, Nclamp);
        unsigned int u0 = *(const unsigned int*)(hs + (size_t)iv.x * OUT_CH + 2 * ch2);
        unsigned int u1 = *(const unsigned int*)(hs + (size_t)iv.y * OUT_CH + 2 * ch2);
        unsigned int u2 = *(const unsigned int*)(hs + (size_t)iv.z * OUT_CH + 2 * ch2);
        unsigned int u3 = *(const unsigned int*)(hs + (size_t)iv.w * OUT_CH + 2 * ch2);
        acc0 += bflo(u0) + bflo(u1) + bflo(u2) + bflo(u3);
        acc1 += bfhi(u0) + bfhi(u1) + bfhi(u2) + bfhi(u3);
    }
    acc0 += __shfl_xor(acc0, 32, 64);
    acc1 += __shfl_xor(acc1, 32, 64);
    unsigned int us = *(const unsigned int*)(hs + (size_t)node * OUT_CH + 2 * ch2);
    acc0 += bflo(us);
    acc1 += bfhi(us);
    float di = dinv[node];
    float2 bb = *(const float2*)(bias + 2 * ch2);
    float v0 = fmaf(acc0, di, bb.x);
    float v1 = fmaf(acc1, di, bb.y);
    float mx = fmaxf(v0, v1);
#pragma unroll
    for (int off = 16; off > 0; off >>= 1) mx = fmaxf(mx, __shfl_xor(mx, off, 64));
    float s = expf(v0 - mx) + expf(v1 - mx);
#pragma unroll
    for (int off = 16; off > 0; off >>= 1) s += __shfl_xor(s, off, 64);
    float ls = logf(s);
    if (sub == 0) {
        float2 o = {v0 - mx - ls, v1 - mx - ls};
        *(float2*)(out + (size_t)node * OUT_CH + 2 * ch2) = o;
    }
}

extern "C" void kernel_launch(void* const* d_in, const int* in_sizes, int n_in,
                              void* d_out, int out_size, void* d_ws, size_t ws_size,
                              hipStream_t stream) {
    const float* x  = (const float*)d_in[0];
    const int*   ei = (const int*)d_in[1];
    const float* W  = (const float*)d_in[2];
    const float* b  = (const float*)d_in[3];
    float* out = (float*)d_out;

    const int N = in_sizes[0] / IN_CH;   // 100000
    const int E = in_sizes[1] / 2;       // 1600000

    char* ws = (char*)d_ws;
    size_t o = 0;
    auto alloc = [&](size_t bytes) { void* p = ws + o; o += (bytes + 63) & ~(size_t)63; return p; };
    unsigned int* cnt      = (unsigned int*)alloc((size_t)N * 4);
    unsigned int* cursor   = (unsigned int*)alloc((size_t)N * 4);
    unsigned int* rowptr   = (unsigned int*)alloc((size_t)N * 4);
    unsigned int* wavesum  = (unsigned int*)alloc(8192 * 4);
    unsigned int* waveoff  = (unsigned int*)alloc(8192 * 4);
    float*        dinv     = (float*)alloc((size_t)N * 4);
    unsigned int* srcIdx   = (unsigned int*)alloc(((size_t)E + 7 * (size_t)N + 64) * 4);
    unsigned short* Wt     = (unsigned short*)alloc((size_t)IN_CH * OUT_CH * 2);
    unsigned short* hs     = (unsigned short*)alloc((size_t)(N + 1) * OUT_CH * 2);

    // cooperative grid: fill the device up to co-residency limit, cap 1024 blocks
    int maxBlocksPerCU = 0;
    hipOccupancyMaxActiveBlocksPerMultiprocessor(&maxBlocksPerCU, coop1_kernel, 256, 0);
    if (maxBlocksPerCU < 1) maxBlocksPerCU = 1;
    int coopBlocks = maxBlocksPerCU * 256;   // 256 CUs on gfx950
    if (coopBlocks > 1024) coopBlocks = 1024;
    if (coopBlocks < 256) coopBlocks = 256;

    int N_ = N, E_ = E;
    void* args[] = {
        (void*)&W, (void*)&ei, (void*)&cnt, (void*)&cursor, (void*)&rowptr,
        (void*)&wavesum, (void*)&waveoff, (void*)&dinv, (void*)&srcIdx,
        (void*)&Wt, (void*)&hs, (void*)&N_, (void*)&E_
    };
    hipLaunchCooperativeKernel((void*)coop1_kernel, dim3(coopBlocks), dim3(256),
                               args, 0, stream);

    gemm_mfma<<<((N + 15) / 16 * 64 + 255) / 256, 256, 0, stream>>>(x, Wt, dinv, hs, N);
    gather_kernel<<<((size_t)N * 64 + 255) / 256, 256, 0, stream>>>(srcIdx, rowptr, cnt, dinv, hs, b, out, N);
}

// Round 5
// 568.383 us; speedup vs baseline: 1.9057x; 1.9057x over previous
//
#include <hip/hip_runtime.h>
#include <hip/hip_bf16.h>

#define IN_CH 512
#define OUT_CH 64
#define SCAN_CHUNK 2048   // 256 threads * 8 elements

typedef __attribute__((ext_vector_type(8))) short short8;
typedef __attribute__((ext_vector_type(4))) float f32x4;

static __device__ __forceinline__ unsigned short bf16bits(float f) {
    __hip_bfloat16 h = __float2bfloat16(f);
    return *reinterpret_cast<unsigned short*>(&h);
}
static __device__ __forceinline__ float bflo(unsigned int u) { return __uint_as_float(u << 16); }
static __device__ __forceinline__ float bfhi(unsigned int u) { return __uint_as_float(u & 0xffff0000u); }

// ============ prep: W->Wt bf16 transpose + hs sentinel row + degree histogram ============
// blocks [0,127]: Wt; block 128: zero hs row N; blocks >=129: degree atomics.
__global__ void __launch_bounds__(256) prep_kernel(const float* __restrict__ W,
                                                   const int* __restrict__ ei,
                                                   unsigned short* __restrict__ Wt,
                                                   unsigned short* __restrict__ hs,
                                                   unsigned int* __restrict__ cnt,
                                                   int N, int E) {
    int b = blockIdx.x;
    if (b < 128) {
        int i = b * 256 + threadIdx.x;   // 32768 total
        int k = i >> 6, n = i & 63;
        Wt[n * IN_CH + k] = bf16bits(W[i]);
    } else if (b == 128) {
        if (threadIdx.x < OUT_CH / 2) ((unsigned int*)(hs + (size_t)N * OUT_CH))[threadIdx.x] = 0u;
    } else {
        const int* col = ei + E;
        int E4 = E >> 2;
        int i = (b - 129) * 256 + threadIdx.x;
        if (i < E4) {
            int4 c = ((const int4*)col)[i];
            atomicAdd(&cnt[c.x], 1u); atomicAdd(&cnt[c.y], 1u);
            atomicAdd(&cnt[c.z], 1u); atomicAdd(&cnt[c.w], 1u);
        } else if (i == E4) {
            for (int e = E4 << 2; e < E; ++e) atomicAdd(&cnt[col[e]], 1u);
        }
    }
}

// ============ scan A: per-chunk exclusive scan of PADDED counts; also dinv ============
__global__ void scan_a(const unsigned int* __restrict__ cnt, float* __restrict__ dinv,
                       unsigned int* __restrict__ rowptr, unsigned int* __restrict__ blockSums, int N) {
    __shared__ unsigned int wsum[4];
    int t = threadIdx.x, b = blockIdx.x;
    int base = b * SCAN_CHUNK + t * 8;
    unsigned int p[8];
    unsigned int run = 0;
#pragma unroll
    for (int j = 0; j < 8; ++j) {
        unsigned int v = (base + j < N) ? cnt[base + j] : 0u;
        if (base + j < N) dinv[base + j] = rsqrtf((float)(v + 1u));
        p[j] = run;
        run += (v + 7u) & ~7u;   // padded count (multiple of 8)
    }
    unsigned int s = run;
    unsigned int si = s;
#pragma unroll
    for (int off = 1; off < 64; off <<= 1) {
        unsigned int o = __shfl_up(si, off, 64);
        if ((t & 63) >= off) si += o;
    }
    if ((t & 63) == 63) wsum[t >> 6] = si;
    __syncthreads();
    unsigned int woff = 0;
    int w = t >> 6;
    for (int k = 0; k < w; ++k) woff += wsum[k];
    unsigned int exc = woff + si - s;
#pragma unroll
    for (int j = 0; j < 8; ++j)
        if (base + j < N) rowptr[base + j] = exc + p[j];   // block-local for now
    if (t == 255) blockSums[b] = woff + si;
}

// ============ scan B: exclusive scan of block totals (single wave, nb<=64) ============
__global__ void scan_b(const unsigned int* __restrict__ blockSums, unsigned int* __restrict__ blockOff, int nb) {
    int t = threadIdx.x;
    unsigned int s = (t < nb) ? blockSums[t] : 0u;
    unsigned int si = s;
#pragma unroll
    for (int off = 1; off < 64; off <<= 1) {
        unsigned int o = __shfl_up(si, off, 64);
        if (t >= off) si += o;
    }
    blockOff[t] = si - s;
}

// ============ scan C: globalize rowptr, seed cursor, write pad sentinels ============
__global__ void scan_c(unsigned int* __restrict__ rowptr, unsigned int* __restrict__ cursor,
                       const unsigned int* __restrict__ blockOff, const unsigned int* __restrict__ cnt,
                       unsigned int* __restrict__ srcIdx, int N) {
    int i = blockIdx.x * 256 + threadIdx.x;
    if (i >= N) return;
    unsigned int start = rowptr[i] + blockOff[i >> 11];
    rowptr[i] = start;
    cursor[i] = start;
    unsigned int v = cnt[i], pv = (v + 7u) & ~7u;
    for (unsigned int j = v; j < pv; ++j) srcIdx[start + j] = (unsigned int)N;
}

// ============ MFMA bf16 GEMM: hs = bf16((x @ W) * dinv). 32 rows/wave, shared B. ============
__global__ void __launch_bounds__(256) gemm_mfma(const float* __restrict__ x,
                                                 const unsigned short* __restrict__ Wt,
                                                 const float* __restrict__ dinv,
                                                 unsigned short* __restrict__ hs, int N) {
    int wid = (int)((blockIdx.x * (unsigned long long)blockDim.x + threadIdx.x) >> 6);
    int lane = threadIdx.x & 63;
    int row0 = wid * 32;
    if (row0 >= N) return;
    int m = lane & 15, q = lane >> 4;
    const float* xr0 = x + (size_t)(row0 + m) * IN_CH + q * 8;
    const float* xr1 = xr0 + (size_t)16 * IN_CH;
    f32x4 acc[2][4];
#pragma unroll
    for (int u = 0; u < 2; ++u)
#pragma unroll
        for (int t = 0; t < 4; ++t) acc[u][t] = (f32x4){0.f, 0.f, 0.f, 0.f};

#pragma unroll 4
    for (int kb = 0; kb < IN_CH; kb += 32) {
        f32x4 a00 = *(const f32x4*)(xr0 + kb);
        f32x4 a01 = *(const f32x4*)(xr0 + kb + 4);
        f32x4 a10 = *(const f32x4*)(xr1 + kb);
        f32x4 a11 = *(const f32x4*)(xr1 + kb + 4);
        short8 af0, af1;
#pragma unroll
        for (int j = 0; j < 4; ++j) {
            af0[j]     = (short)bf16bits(a00[j]);
            af0[j + 4] = (short)bf16bits(a01[j]);
            af1[j]     = (short)bf16bits(a10[j]);
            af1[j + 4] = (short)bf16bits(a11[j]);
        }
#pragma unroll
        for (int t = 0; t < 4; ++t) {
            short8 bf = *(const short8*)(Wt + (size_t)(t * 16 + m) * IN_CH + kb + q * 8);
            acc[0][t] = __builtin_amdgcn_mfma_f32_16x16x32_bf16(af0, bf, acc[0][t], 0, 0, 0);
            acc[1][t] = __builtin_amdgcn_mfma_f32_16x16x32_bf16(af1, bf, acc[1][t], 0, 0, 0);
        }
    }
    // C/D layout: col = lane&15, row (within 16) = q*4 + reg
#pragma unroll
    for (int u = 0; u < 2; ++u) {
#pragma unroll
        for (int r = 0; r < 4; ++r) {
            int row = row0 + u * 16 + q * 4 + r;
            if (row < N) {
                float dr = dinv[row];
#pragma unroll
                for (int t = 0; t < 4; ++t)
                    hs[(size_t)row * OUT_CH + t * 16 + m] = bf16bits(acc[u][t][r] * dr);
            }
        }
    }
}

// ============ fill CSR: single pre-seeded atomic per edge ============
__global__ void fill_kernel(const int* __restrict__ ei, unsigned int* __restrict__ cursor,
                            unsigned int* __restrict__ srcIdx, int E) {
    int E4 = E >> 2;
    int i = blockIdx.x * 256 + threadIdx.x;
    if (i < E4) {
        int4 r = ((const int4*)ei)[i];
        int4 c = ((const int4*)(ei + E))[i];
        unsigned int pos;
        pos = atomicAdd(&cursor[c.x], 1u); srcIdx[pos] = (unsigned int)r.x;
        pos = atomicAdd(&cursor[c.y], 1u); srcIdx[pos] = (unsigned int)r.y;
        pos = atomicAdd(&cursor[c.z], 1u); srcIdx[pos] = (unsigned int)r.z;
        pos = atomicAdd(&cursor[c.w], 1u); srcIdx[pos] = (unsigned int)r.w;
    } else if (i == E4) {
        for (int e = E4 << 2; e < E; ++e) {
            unsigned int pos = atomicAdd(&cursor[ei[E + e]], 1u);
            srcIdx[pos] = (unsigned int)ei[e];
        }
    }
}

// ============ gather + self + bias + log_softmax, 2x unrolled ============
__global__ void __launch_bounds__(256) gather_kernel(const unsigned int* __restrict__ srcIdx,
                                                     const unsigned int* __restrict__ rowptr,
                                                     const unsigned int* __restrict__ cnt,
                                                     const float* __restrict__ dinv,
                                                     const unsigned short* __restrict__ hs,
                                                     const float* __restrict__ bias,
                                                     float* __restrict__ out, int N) {
    int node = (int)((blockIdx.x * (unsigned long long)blockDim.x + threadIdx.x) >> 6);
    int lane = threadIdx.x & 63;
    if (node >= N) return;
    int sub = lane >> 5, ch2 = lane & 31;
    unsigned int start = rowptr[node];
    unsigned int iters = (cnt[node] + 7u) >> 3;   // 8 entries per iter (4 per half-wave)
    const uint4* p = (const uint4*)(srcIdx + start) + sub;   // start is 8-aligned => 16B aligned
    float acc0 = 0.f, acc1 = 0.f;
    unsigned int pairs = iters >> 1;
    for (unsigned int it = 0; it < pairs; ++it) {
        uint4 iv0 = p[0];
        uint4 iv1 = p[2];
        p += 4;
        unsigned int u0 = *(const unsigned int*)(hs + (size_t)iv0.x * OUT_CH + 2 * ch2);
        unsigned int u1 = *(const unsigned int*)(hs + (size_t)iv0.y * OUT_CH + 2 * ch2);
        unsigned int u2 = *(const unsigned int*)(hs + (size_t)iv0.z * OUT_CH + 2 * ch2);
        unsigned int u3 = *(const unsigned int*)(hs + (size_t)iv0.w * OUT_CH + 2 * ch2);
        unsigned int u4 = *(const unsigned int*)(hs + (size_t)iv1.x * OUT_CH + 2 * ch2);
        unsigned int u5 = *(const unsigned int*)(hs + (size_t)iv1.y * OUT_CH + 2 * ch2);
        unsigned int u6 = *(const unsigned int*)(hs + (size_t)iv1.z * OUT_CH + 2 * ch2);
        unsigned int u7 = *(const unsigned int*)(hs + (size_t)iv1.w * OUT_CH + 2 * ch2);
        acc0 += (bflo(u0) + bflo(u1)) + (bflo(u2) + bflo(u3)) + (bflo(u4) + bflo(u5)) + (bflo(u6) + bflo(u7));
        acc1 += (bfhi(u0) + bfhi(u1)) + (bfhi(u2) + bfhi(u3)) + (bfhi(u4) + bfhi(u5)) + (bfhi(u6) + bfhi(u7));
    }
    if (iters & 1u) {
        uint4 iv = p[0];
        unsigned int u0 = *(const unsigned int*)(hs + (size_t)iv.x * OUT_CH + 2 * ch2);
        unsigned int u1 = *(const unsigned int*)(hs + (size_t)iv.y * OUT_CH + 2 * ch2);
        unsigned int u2 = *(const unsigned int*)(hs + (size_t)iv.z * OUT_CH + 2 * ch2);
        unsigned int u3 = *(const unsigned int*)(hs + (size_t)iv.w * OUT_CH + 2 * ch2);
        acc0 += (bflo(u0) + bflo(u1)) + (bflo(u2) + bflo(u3));
        acc1 += (bfhi(u0) + bfhi(u1)) + (bfhi(u2) + bfhi(u3));
    }
    acc0 += __shfl_xor(acc0, 32, 64);
    acc1 += __shfl_xor(acc1, 32, 64);
    // self-loop + scale + bias
    unsigned int us = *(const unsigned int*)(hs + (size_t)node * OUT_CH + 2 * ch2);
    acc0 += bflo(us);
    acc1 += bfhi(us);
    float di = dinv[node];
    float2 bb = *(const float2*)(bias + 2 * ch2);
    float v0 = fmaf(acc0, di, bb.x);
    float v1 = fmaf(acc1, di, bb.y);
    float mx = fmaxf(v0, v1);
#pragma unroll
    for (int off = 16; off > 0; off >>= 1) mx = fmaxf(mx, __shfl_xor(mx, off, 64));
    float s = expf(v0 - mx) + expf(v1 - mx);
#pragma unroll
    for (int off = 16; off > 0; off >>= 1) s += __shfl_xor(s, off, 64);
    float ls = logf(s);
    if (sub == 0) {
        float2 o = {v0 - mx - ls, v1 - mx - ls};
        *(float2*)(out + (size_t)node * OUT_CH + 2 * ch2) = o;
    }
}

extern "C" void kernel_launch(void* const* d_in, const int* in_sizes, int n_in,
                              void* d_out, int out_size, void* d_ws, size_t ws_size,
                              hipStream_t stream) {
    const float* x  = (const float*)d_in[0];
    const int*   ei = (const int*)d_in[1];
    const float* W  = (const float*)d_in[2];
    const float* b  = (const float*)d_in[3];
    float* out = (float*)d_out;

    const int N = in_sizes[0] / IN_CH;   // 100000
    const int E = in_sizes[1] / 2;       // 1600000
    const int NBLK = (N + SCAN_CHUNK - 1) / SCAN_CHUNK;  // 49

    char* ws = (char*)d_ws;
    size_t o = 0;
    auto alloc = [&](size_t bytes) { void* p = ws + o; o += (bytes + 63) & ~(size_t)63; return p; };
    unsigned int* cnt      = (unsigned int*)alloc((size_t)N * 4);
    unsigned int* cursor   = (unsigned int*)alloc((size_t)N * 4);
    unsigned int* rowptr   = (unsigned int*)alloc((size_t)N * 4);
    unsigned int* blockSums= (unsigned int*)alloc(256);
    unsigned int* blockOff = (unsigned int*)alloc(256);
    float*        dinv     = (float*)alloc((size_t)N * 4);
    unsigned int* srcIdx   = (unsigned int*)alloc(((size_t)E + 7 * (size_t)N + 64) * 4);
    unsigned short* Wt     = (unsigned short*)alloc((size_t)IN_CH * OUT_CH * 2);
    unsigned short* hs     = (unsigned short*)alloc((size_t)(N + 1) * OUT_CH * 2);

    hipMemsetAsync(cnt, 0, (size_t)N * 4, stream);

    int degBlocks = (E / 4 + 256) / 256;
    prep_kernel<<<129 + degBlocks, 256, 0, stream>>>(W, ei, Wt, hs, cnt, N, E);
    scan_a<<<NBLK, 256, 0, stream>>>(cnt, dinv, rowptr, blockSums, N);
    scan_b<<<1, 64, 0, stream>>>(blockSums, blockOff, NBLK);
    scan_c<<<(N + 255) / 256, 256, 0, stream>>>(rowptr, cursor, blockOff, cnt, srcIdx, N);
    gemm_mfma<<<(((N + 31) / 32) * 64 + 255) / 256, 256, 0, stream>>>(x, Wt, dinv, hs, N);
    fill_kernel<<<(E / 4 + 256) / 256, 256, 0, stream>>>(ei, cursor, srcIdx, E);
    gather_kernel<<<((size_t)N * 64 + 255) / 256, 256, 0, stream>>>(srcIdx, rowptr, cnt, dinv, hs, b, out, N);
}